// Round 1
// baseline (2087.479 us; speedup 1.0000x reference)
//
#include <hip/hip_runtime.h>
#include <math.h>

#define NN 8
#define SS 2
#define LL 512
#define EE 1024
#define HH 16
#define DD 64
#define NSX (NN*SS)          // 16
#define NT (NSX*LL)          // 8192 tokens
#define NSLE (NT*EE)         // 8388608
#define NSHL (NSX*HH*LL)     // 131072
#define INV_SQRT_L 0.04419417382415922f   // 1/sqrt(512)

// ---------------- K1: per-head projections q,k,v ----------------
// one block per token; 12 outputs/thread (3 mats * 16 heads * 64 d / 256 thr)
__global__ void __launch_bounds__(256) proj_kernel(
    const float* __restrict__ vals, const float* __restrict__ keys,
    const float* __restrict__ qry,
    const float* __restrict__ Wv, const float* __restrict__ Wk,
    const float* __restrict__ Wq,
    float* __restrict__ vp, float* __restrict__ kp, float* __restrict__ qp) {
  __shared__ float sx[3][EE];
  const int t = blockIdx.x;
  const int tid = threadIdx.x;
  for (int i = tid; i < EE; i += 256) {
    sx[0][i] = vals[(size_t)t*EE + i];
    sx[1][i] = keys[(size_t)t*EE + i];
    sx[2][i] = qry [(size_t)t*EE + i];
  }
  __syncthreads();
  #pragma unroll
  for (int o = 0; o < 12; ++o) {
    int flat = o*256 + tid;
    int mat = flat >> 10, rem = flat & 1023;
    int h = rem >> 6, d = rem & 63;
    const float* w = (mat == 0 ? Wv : mat == 1 ? Wk : Wq) + d*DD;
    const float* x = &sx[mat][h*DD];
    float acc = 0.f;
    #pragma unroll
    for (int j = 0; j < DD; j += 4) {
      float4 wv = *(const float4*)(w + j);
      acc += x[j]*wv.x + x[j+1]*wv.y + x[j+2]*wv.z + x[j+3]*wv.w;
    }
    float* dst = (mat == 0 ? vp : mat == 1 ? kp : qp);
    dst[(size_t)t*EE + rem] = acc;
  }
}

// ---------------- K2: per-column (key index l) softmax stats over q ----------------
// softmax is over the QUERY axis; mask kills query rows.
// block = (ns, h, l-tile of 64 columns); thread group of 4 lanes shares a column.
__global__ void __launch_bounds__(256) colstats_kernel(
    const float* __restrict__ qp, const float* __restrict__ kp,
    const int* __restrict__ mask,
    float* __restrict__ colm, float* __restrict__ colsinv) {
  const int b = blockIdx.x;           // 16*16*8 = 2048
  const int ct = b & 7, h = (b >> 3) & 15, ns = b >> 7;
  const int tid = threadIdx.x;
  const int cl = tid >> 2, dg = tid & 3;
  const int l = ct*64 + cl;
  float kreg[16];
  const float* krow = kp + (size_t)(ns*LL + l)*EE + h*DD + dg*16;
  #pragma unroll
  for (int j = 0; j < 16; j += 4) {
    float4 kv = *(const float4*)(krow + j);
    kreg[j] = kv.x; kreg[j+1] = kv.y; kreg[j+2] = kv.z; kreg[j+3] = kv.w;
  }
  __shared__ float qt_s[32][DD];
  __shared__ int mk_s[32];
  float m = -INFINITY, s = 0.f;
  const float* qbase = qp + (size_t)(ns*LL)*EE + h*DD;
  const int* mbase = mask + ns*LL;
  for (int q0 = 0; q0 < LL; q0 += 32) {
    for (int i = tid; i < 32*DD; i += 256) {
      int r = i >> 6, c = i & 63;
      qt_s[r][c] = qbase[(size_t)(q0 + r)*EE + c];
    }
    if (tid < 32) mk_s[tid] = mbase[q0 + tid];
    __syncthreads();
    float er[32];
    #pragma unroll
    for (int r = 0; r < 32; ++r) {
      float p = 0.f;
      #pragma unroll
      for (int j = 0; j < 16; j += 4) {
        float4 qv = *(const float4*)&qt_s[r][dg*16 + j];
        p += qv.x*kreg[j] + qv.y*kreg[j+1] + qv.z*kreg[j+2] + qv.w*kreg[j+3];
      }
      p += __shfl_xor(p, 1);
      p += __shfl_xor(p, 2);
      er[r] = mk_s[r] ? p * INV_SQRT_L : -INFINITY;
    }
    float tm = -INFINITY;
    #pragma unroll
    for (int r = 0; r < 32; ++r) tm = fmaxf(tm, er[r]);
    float mn = fmaxf(m, tm);
    if (mn != -INFINITY) {   // at least one unmasked q seen so far
      float acc = 0.f;
      #pragma unroll
      for (int r = 0; r < 32; ++r) acc += __expf(er[r] - mn);  // exp(-inf)=0 for masked
      s = s*__expf(m - mn) + acc;  // m=-inf -> exp(-inf)=0, s was 0
      m = mn;
    }
    __syncthreads();
  }
  if (dg == 0) {
    if (!(s > 0.f)) { m = 0.f; s = 1.f; }   // all-masked column guard
    colm[(ns*HH + h)*LL + l] = m;
    colsinv[(ns*HH + h)*LL + l] = 1.0f / s;
  }
}

// ---------------- K3: recompute energy, apply softmax, accumulate out = attn @ v ----
// block = (ns, h, q-tile of 64); 4 lanes per q row, 16 d each; stream l in tiles of 32.
#define LT3 32
__global__ void __launch_bounds__(256) attnout_kernel(
    const float* __restrict__ qp, const float* __restrict__ kp,
    const float* __restrict__ vp, const int* __restrict__ mask,
    const float* __restrict__ colm, const float* __restrict__ colsinv,
    float* __restrict__ oat) {
  const int b = blockIdx.x;           // 2048
  const int qt = b & 7, h = (b >> 3) & 15, ns = b >> 7;
  const int tid = threadIdx.x;
  const int ql = tid >> 2, dg = tid & 3;
  const int q = qt*64 + ql;
  __shared__ float kt[LT3][DD], vt[LT3][DD];
  __shared__ float sm[LT3], ssi[LT3];
  float qreg[16], acc[16];
  const float* qrow = qp + (size_t)(ns*LL + q)*EE + h*DD + dg*16;
  #pragma unroll
  for (int j = 0; j < 16; j += 4) {
    float4 v4 = *(const float4*)(qrow + j);
    qreg[j] = v4.x; qreg[j+1] = v4.y; qreg[j+2] = v4.z; qreg[j+3] = v4.w;
  }
  #pragma unroll
  for (int j = 0; j < 16; ++j) acc[j] = 0.f;
  const bool mq = mask[ns*LL + q] != 0;
  const float* kbase = kp + (size_t)(ns*LL)*EE + h*DD;
  const float* vbase = vp + (size_t)(ns*LL)*EE + h*DD;
  const float* mbase = colm + (ns*HH + h)*LL;
  const float* sbase = colsinv + (ns*HH + h)*LL;
  for (int lt = 0; lt < LL; lt += LT3) {
    for (int i = tid; i < LT3*DD; i += 256) {
      int r = i >> 6, c = i & 63;
      kt[r][c] = kbase[(size_t)(lt + r)*EE + c];
      vt[r][c] = vbase[(size_t)(lt + r)*EE + c];
    }
    if (tid < LT3) { sm[tid] = mbase[lt + tid]; ssi[tid] = sbase[lt + tid]; }
    __syncthreads();
    #pragma unroll 4
    for (int l = 0; l < LT3; ++l) {
      float p = 0.f;
      #pragma unroll
      for (int j = 0; j < 16; j += 4) {
        float4 kv = *(const float4*)&kt[l][dg*16 + j];
        p += qreg[j]*kv.x + qreg[j+1]*kv.y + qreg[j+2]*kv.z + qreg[j+3]*kv.w;
      }
      p += __shfl_xor(p, 1);
      p += __shfl_xor(p, 2);
      float a = mq ? __expf(p*INV_SQRT_L - sm[l]) * ssi[l] : 0.f;
      #pragma unroll
      for (int j = 0; j < 16; j += 4) {
        float4 vv = *(const float4*)&vt[l][dg*16 + j];
        acc[j]   += a*vv.x; acc[j+1] += a*vv.y;
        acc[j+2] += a*vv.z; acc[j+3] += a*vv.w;
      }
    }
    __syncthreads();
  }
  float* orow = oat + (size_t)(ns*LL + q)*EE + h*DD + dg*16;
  #pragma unroll
  for (int j = 0; j < 16; j += 4) {
    *(float4*)(orow + j) = make_float4(acc[j], acc[j+1], acc[j+2], acc[j+3]);
  }
}

// ---------------- K4: Y = oat @ Wo^T + bo  (8192x1024 @ 1024x1024) ----------------
// 64x64 tile, 256 threads, 4x4 per thread, K-chunks of 16, K-major LDS for float4 reads.
__global__ void __launch_bounds__(256) out_gemm_kernel(
    const float* __restrict__ A, const float* __restrict__ Wo,
    const float* __restrict__ bo, float* __restrict__ Y) {
  __shared__ float As[16][68], Bs[16][68];
  const int bx = blockIdx.x & 15, by = blockIdx.x >> 4;
  const int tid = threadIdx.x;
  const int tx = tid & 15, ty = tid >> 4;
  const int m0 = by*64, n0 = bx*64;
  float acc[4][4] = {{0.f}};
  for (int k0 = 0; k0 < EE; k0 += 16) {
    for (int i = tid; i < 1024; i += 256) {
      int r = i >> 4, kk = i & 15;
      As[kk][r] = A [(size_t)(m0 + r)*EE + k0 + kk];
      Bs[kk][r] = Wo[(size_t)(n0 + r)*EE + k0 + kk];
    }
    __syncthreads();
    #pragma unroll
    for (int kk = 0; kk < 16; ++kk) {
      float4 a = *(const float4*)&As[kk][ty*4];
      float4 b = *(const float4*)&Bs[kk][tx*4];
      acc[0][0] += a.x*b.x; acc[0][1] += a.x*b.y; acc[0][2] += a.x*b.z; acc[0][3] += a.x*b.w;
      acc[1][0] += a.y*b.x; acc[1][1] += a.y*b.y; acc[1][2] += a.y*b.z; acc[1][3] += a.y*b.w;
      acc[2][0] += a.z*b.x; acc[2][1] += a.z*b.y; acc[2][2] += a.z*b.z; acc[2][3] += a.z*b.w;
      acc[3][0] += a.w*b.x; acc[3][1] += a.w*b.y; acc[3][2] += a.w*b.z; acc[3][3] += a.w*b.w;
    }
    __syncthreads();
  }
  float4 bv = *(const float4*)&bo[n0 + tx*4];
  #pragma unroll
  for (int i = 0; i < 4; ++i) {
    int row = m0 + ty*4 + i;
    *(float4*)&Y[(size_t)row*EE + n0 + tx*4] =
        make_float4(acc[i][0]+bv.x, acc[i][1]+bv.y, acc[i][2]+bv.z, acc[i][3]+bv.w);
  }
}

extern "C" void kernel_launch(void* const* d_in, const int* in_sizes, int n_in,
                              void* d_out, int out_size, void* d_ws, size_t ws_size,
                              hipStream_t stream) {
  const float* values = (const float*)d_in[0];
  const float* keysp  = (const float*)d_in[1];
  const float* query  = (const float*)d_in[2];
  const int*   mask   = (const int*)d_in[3];
  const float* Wv = (const float*)d_in[4];
  const float* Wk = (const float*)d_in[5];
  const float* Wq = (const float*)d_in[6];
  const float* Wo = (const float*)d_in[7];
  const float* bo = (const float*)d_in[8];
  float* Y = (float*)d_out;

  // workspace layout (floats): qp | kp | vp | colm | colsinv | oat  = 135.3 MB
  float* ws = (float*)d_ws;
  float* qp    = ws;
  float* kp    = qp + NSLE;
  float* vp    = kp + NSLE;
  float* colm  = vp + NSLE;
  float* colsi = colm + NSHL;
  float* oat   = colsi + NSHL;

  proj_kernel<<<NT, 256, 0, stream>>>(values, keysp, query, Wv, Wk, Wq, vp, kp, qp);
  colstats_kernel<<<NSX*HH*(LL/64), 256, 0, stream>>>(qp, kp, mask, colm, colsi);
  attnout_kernel<<<NSX*HH*(LL/64), 256, 0, stream>>>(qp, kp, vp, mask, colm, colsi, oat);
  out_gemm_kernel<<<(NT/64)*(EE/64), 256, 0, stream>>>(oat, Wo, bo, Y);
}

// Round 2
// 1184.850 us; speedup vs baseline: 1.7618x; 1.7618x over previous
//
#include <hip/hip_runtime.h>
#include <math.h>

#define NN 8
#define SS 2
#define LL 512
#define EE 1024
#define HH 16
#define DD 64
#define NSX (NN*SS)          // 16
#define NT (NSX*LL)          // 8192 tokens
#define NSLE (NT*EE)         // 8388608
#define NSHL (NSX*HH*LL)     // 131072
#define INV_SQRT_L 0.04419417382415922f   // 1/sqrt(512)

// ---------------- K1: projections as tiled GEMM ----------------
// grid = 3 mats x 16 ns x 16 heads x 8 token-tiles = 6144 blocks.
// 64 tok x 64 d tile, K=64, k-major LDS, 4x4 register frags.
__global__ void __launch_bounds__(256) proj_kernel(
    const float* __restrict__ vals, const float* __restrict__ keys,
    const float* __restrict__ qry,
    const float* __restrict__ Wv, const float* __restrict__ Wk,
    const float* __restrict__ Wq,
    float* __restrict__ vp, float* __restrict__ kp, float* __restrict__ qp) {
  __shared__ float Xs[64][68];   // Xs[k][t]
  __shared__ float Ws[64][68];   // Ws[k][d]
  const int b = blockIdx.x;
  const int qt = b & 7, h = (b >> 3) & 15, ns = (b >> 7) & 15, mat = b >> 11;
  const int tid = threadIdx.x;
  const float* src = (mat == 0 ? vals : mat == 1 ? keys : qry);
  const float* W   = (mat == 0 ? Wv   : mat == 1 ? Wk   : Wq);
  float* dst       = (mat == 0 ? vp   : mat == 1 ? kp   : qp);
  const int t0 = qt * 64;
  const size_t xbase = ((size_t)(ns*LL + t0))*EE + h*DD;
  for (int i = tid; i < 4096; i += 256) {
    int r = i >> 6, k = i & 63;           // r = token (X) / output-dim (W)
    Xs[k][r] = src[xbase + (size_t)r*EE + k];
    Ws[k][r] = W[r*DD + k];
  }
  __syncthreads();
  const int tx = tid & 15, ty = tid >> 4;
  float acc[4][4] = {{0.f}};
  #pragma unroll 16
  for (int k = 0; k < 64; ++k) {
    float4 a = *(const float4*)&Xs[k][ty*4];
    float4 c = *(const float4*)&Ws[k][tx*4];
    acc[0][0] += a.x*c.x; acc[0][1] += a.x*c.y; acc[0][2] += a.x*c.z; acc[0][3] += a.x*c.w;
    acc[1][0] += a.y*c.x; acc[1][1] += a.y*c.y; acc[1][2] += a.y*c.z; acc[1][3] += a.y*c.w;
    acc[2][0] += a.z*c.x; acc[2][1] += a.z*c.y; acc[2][2] += a.z*c.z; acc[2][3] += a.z*c.w;
    acc[3][0] += a.w*c.x; acc[3][1] += a.w*c.y; acc[3][2] += a.w*c.z; acc[3][3] += a.w*c.w;
  }
  #pragma unroll
  for (int i = 0; i < 4; ++i) {
    *(float4*)&dst[((size_t)(ns*LL + t0 + ty*4 + i))*EE + h*DD + tx*4] =
        make_float4(acc[i][0], acc[i][1], acc[i][2], acc[i][3]);
  }
}

// ---------------- K2: per-column softmax stats (softmax is over q!) ----------
// block = (ns, h, l-tile of 128); each 4-lane group owns 2 columns.
__global__ void __launch_bounds__(256) colstats_kernel(
    const float* __restrict__ qp, const float* __restrict__ kp,
    const int* __restrict__ mask,
    float* __restrict__ colm, float* __restrict__ colsinv) {
  const int b = blockIdx.x;           // 16*16*4 = 1024
  const int lt = b & 3, h = (b >> 2) & 15, ns = b >> 6;
  const int tid = threadIdx.x;
  const int cl = tid >> 2, dg = tid & 3;
  const int l0 = lt*128 + cl*2;
  float kreg[2][16];
  #pragma unroll
  for (int c = 0; c < 2; ++c) {
    const float* krow = kp + (size_t)(ns*LL + l0 + c)*EE + h*DD + dg*16;
    #pragma unroll
    for (int j = 0; j < 16; j += 4) {
      float4 kv = *(const float4*)(krow + j);
      kreg[c][j] = kv.x; kreg[c][j+1] = kv.y; kreg[c][j+2] = kv.z; kreg[c][j+3] = kv.w;
    }
  }
  __shared__ float qt_s[64][68];
  __shared__ int mk_s[64];
  float m0 = -1e30f, s0 = 0.f, m1 = -1e30f, s1 = 0.f;
  const float* qbase = qp + (size_t)(ns*LL)*EE + h*DD;
  const int* mbase = mask + ns*LL;
  for (int q0 = 0; q0 < LL; q0 += 64) {
    __syncthreads();
    for (int i = tid; i < 4096; i += 256) {
      int r = i >> 6, c = i & 63;
      qt_s[r][c] = qbase[(size_t)(q0 + r)*EE + c];
    }
    if (tid < 64) mk_s[tid] = mbase[q0 + tid];
    __syncthreads();
    #pragma unroll 2
    for (int r = 0; r < 64; ++r) {
      float p0 = 0.f, p1 = 0.f;
      #pragma unroll
      for (int j = 0; j < 16; j += 4) {
        float4 qv = *(const float4*)&qt_s[r][dg*16 + j];
        p0 += qv.x*kreg[0][j] + qv.y*kreg[0][j+1] + qv.z*kreg[0][j+2] + qv.w*kreg[0][j+3];
        p1 += qv.x*kreg[1][j] + qv.y*kreg[1][j+1] + qv.z*kreg[1][j+2] + qv.w*kreg[1][j+3];
      }
      p0 += __shfl_xor(p0, 1); p0 += __shfl_xor(p0, 2);
      p1 += __shfl_xor(p1, 1); p1 += __shfl_xor(p1, 2);
      const bool mk = mk_s[r] != 0;
      float es0 = mk ? p0*INV_SQRT_L : -1e30f;
      float nm0 = fmaxf(m0, es0);
      s0 = s0*__expf(m0 - nm0) + (mk ? __expf(es0 - nm0) : 0.f);
      m0 = nm0;
      float es1 = mk ? p1*INV_SQRT_L : -1e30f;
      float nm1 = fmaxf(m1, es1);
      s1 = s1*__expf(m1 - nm1) + (mk ? __expf(es1 - nm1) : 0.f);
      m1 = nm1;
    }
  }
  if (dg == 0) {
    if (!(s0 > 0.f)) { m0 = 0.f; s0 = 1.f; }
    if (!(s1 > 0.f)) { m1 = 0.f; s1 = 1.f; }
    colm   [(ns*HH + h)*LL + l0    ] = m0;
    colsinv[(ns*HH + h)*LL + l0    ] = 1.0f/s0;
    colm   [(ns*HH + h)*LL + l0 + 1] = m1;
    colsinv[(ns*HH + h)*LL + l0 + 1] = 1.0f/s1;
  }
}

// ---------------- K3: recompute energy, weight, accumulate out = attn @ v ----
// block = (ns, h, q-tile of 256); each 4-lane group owns 4 q rows.
#define LT3 32
__global__ void __launch_bounds__(256, 2) attnout_kernel(
    const float* __restrict__ qp, const float* __restrict__ kp,
    const float* __restrict__ vp, const int* __restrict__ mask,
    const float* __restrict__ colm, const float* __restrict__ colsinv,
    float* __restrict__ oat) {
  const int b = blockIdx.x;           // 16*16*2 = 512
  const int qt = b & 1, h = (b >> 1) & 15, ns = b >> 5;
  const int tid = threadIdx.x;
  const int ql = tid >> 2, dg = tid & 3;
  const int qb = qt*256 + ql*4;
  __shared__ float kt[LT3][68], vt[LT3][68];
  __shared__ float sm[LT3], ssi[LT3];
  float qreg[4][16], acc[4][16];
  bool mq[4];
  #pragma unroll
  for (int i = 0; i < 4; ++i) {
    const float* qrow = qp + (size_t)(ns*LL + qb + i)*EE + h*DD + dg*16;
    #pragma unroll
    for (int j = 0; j < 16; j += 4) {
      float4 v4 = *(const float4*)(qrow + j);
      qreg[i][j] = v4.x; qreg[i][j+1] = v4.y; qreg[i][j+2] = v4.z; qreg[i][j+3] = v4.w;
    }
    mq[i] = mask[ns*LL + qb + i] != 0;
    #pragma unroll
    for (int j = 0; j < 16; ++j) acc[i][j] = 0.f;
  }
  const float* kbase = kp + (size_t)(ns*LL)*EE + h*DD;
  const float* vbase = vp + (size_t)(ns*LL)*EE + h*DD;
  const float* mbase = colm + (ns*HH + h)*LL;
  const float* sbase = colsinv + (ns*HH + h)*LL;
  for (int lt = 0; lt < LL; lt += LT3) {
    __syncthreads();
    for (int i = tid; i < LT3*64; i += 256) {
      int r = i >> 6, c = i & 63;
      kt[r][c] = kbase[(size_t)(lt + r)*EE + c];
      vt[r][c] = vbase[(size_t)(lt + r)*EE + c];
    }
    if (tid < LT3) { sm[tid] = mbase[lt + tid]; ssi[tid] = sbase[lt + tid]; }
    __syncthreads();
    #pragma unroll 2
    for (int l = 0; l < LT3; ++l) {
      float p[4] = {0.f, 0.f, 0.f, 0.f};
      #pragma unroll
      for (int j = 0; j < 16; j += 4) {
        float4 kv = *(const float4*)&kt[l][dg*16 + j];
        #pragma unroll
        for (int i = 0; i < 4; ++i)
          p[i] += qreg[i][j]*kv.x + qreg[i][j+1]*kv.y + qreg[i][j+2]*kv.z + qreg[i][j+3]*kv.w;
      }
      float a[4];
      #pragma unroll
      for (int i = 0; i < 4; ++i) {
        p[i] += __shfl_xor(p[i], 1);
        p[i] += __shfl_xor(p[i], 2);
        a[i] = mq[i] ? __expf(p[i]*INV_SQRT_L - sm[l]) * ssi[l] : 0.f;
      }
      #pragma unroll
      for (int j = 0; j < 16; j += 4) {
        float4 vv = *(const float4*)&vt[l][dg*16 + j];
        #pragma unroll
        for (int i = 0; i < 4; ++i) {
          acc[i][j]   += a[i]*vv.x; acc[i][j+1] += a[i]*vv.y;
          acc[i][j+2] += a[i]*vv.z; acc[i][j+3] += a[i]*vv.w;
        }
      }
    }
  }
  #pragma unroll
  for (int i = 0; i < 4; ++i) {
    float* orow = oat + (size_t)(ns*LL + qb + i)*EE + h*DD + dg*16;
    #pragma unroll
    for (int j = 0; j < 16; j += 4)
      *(float4*)(orow + j) = make_float4(acc[i][j], acc[i][j+1], acc[i][j+2], acc[i][j+3]);
  }
}

// ---------------- K4: Y = oat @ Wo^T + bo  (8192x1024 @ 1024x1024) ----------------
__global__ void __launch_bounds__(256) out_gemm_kernel(
    const float* __restrict__ A, const float* __restrict__ Wo,
    const float* __restrict__ bo, float* __restrict__ Y) {
  __shared__ float As[16][68], Bs[16][68];
  const int bx = blockIdx.x & 15, by = blockIdx.x >> 4;
  const int tid = threadIdx.x;
  const int tx = tid & 15, ty = tid >> 4;
  const int m0 = by*64, n0 = bx*64;
  float acc[4][4] = {{0.f}};
  for (int k0 = 0; k0 < EE; k0 += 16) {
    for (int i = tid; i < 1024; i += 256) {
      int r = i >> 4, kk = i & 15;
      As[kk][r] = A [(size_t)(m0 + r)*EE + k0 + kk];
      Bs[kk][r] = Wo[(size_t)(n0 + r)*EE + k0 + kk];
    }
    __syncthreads();
    #pragma unroll
    for (int kk = 0; kk < 16; ++kk) {
      float4 a = *(const float4*)&As[kk][ty*4];
      float4 b = *(const float4*)&Bs[kk][tx*4];
      acc[0][0] += a.x*b.x; acc[0][1] += a.x*b.y; acc[0][2] += a.x*b.z; acc[0][3] += a.x*b.w;
      acc[1][0] += a.y*b.x; acc[1][1] += a.y*b.y; acc[1][2] += a.y*b.z; acc[1][3] += a.y*b.w;
      acc[2][0] += a.z*b.x; acc[2][1] += a.z*b.y; acc[2][2] += a.z*b.z; acc[2][3] += a.z*b.w;
      acc[3][0] += a.w*b.x; acc[3][1] += a.w*b.y; acc[3][2] += a.w*b.z; acc[3][3] += a.w*b.w;
    }
    __syncthreads();
  }
  float4 bv = *(const float4*)&bo[n0 + tx*4];
  #pragma unroll
  for (int i = 0; i < 4; ++i) {
    int row = m0 + ty*4 + i;
    *(float4*)&Y[(size_t)row*EE + n0 + tx*4] =
        make_float4(acc[i][0]+bv.x, acc[i][1]+bv.y, acc[i][2]+bv.z, acc[i][3]+bv.w);
  }
}

extern "C" void kernel_launch(void* const* d_in, const int* in_sizes, int n_in,
                              void* d_out, int out_size, void* d_ws, size_t ws_size,
                              hipStream_t stream) {
  const float* values = (const float*)d_in[0];
  const float* keysp  = (const float*)d_in[1];
  const float* query  = (const float*)d_in[2];
  const int*   mask   = (const int*)d_in[3];
  const float* Wv = (const float*)d_in[4];
  const float* Wk = (const float*)d_in[5];
  const float* Wq = (const float*)d_in[6];
  const float* Wo = (const float*)d_in[7];
  const float* bo = (const float*)d_in[8];
  float* Y = (float*)d_out;

  float* ws = (float*)d_ws;
  float* qp    = ws;
  float* kp    = qp + NSLE;
  float* vp    = kp + NSLE;
  float* colm  = vp + NSLE;
  float* colsi = colm + NSHL;
  float* oat   = colsi + NSHL;

  proj_kernel<<<3*NSX*HH*(LL/64), 256, 0, stream>>>(values, keysp, query, Wv, Wk, Wq, vp, kp, qp);
  colstats_kernel<<<NSX*HH*(LL/128), 256, 0, stream>>>(qp, kp, mask, colm, colsi);
  attnout_kernel<<<NSX*HH*(LL/256), 256, 0, stream>>>(qp, kp, vp, mask, colm, colsi, oat);
  out_gemm_kernel<<<(NT/64)*(EE/64), 256, 0, stream>>>(oat, Wo, bo, Y);
}

// Round 3
// 451.042 us; speedup vs baseline: 4.6281x; 2.6269x over previous
//
#include <hip/hip_runtime.h>
#include <math.h>

#define LL 512
#define EE 1024
#define HH 16
#define DD 64
#define NSX 16               // N*S
#define NT (NSX*LL)          // 8192 tokens
#define NSLE (NT*EE)         // 8388608
#define NSHL (NSX*HH*LL)     // 131072
#define INV_SQRT_L 0.04419417382415922f

typedef unsigned short u16;
typedef short bf16x8 __attribute__((ext_vector_type(8)));
typedef float f32x4 __attribute__((ext_vector_type(4)));

__device__ inline u16 f2bf(float f) {
  unsigned u = __float_as_uint(f);
  u += 0x7fff + ((u >> 16) & 1);          // RNE
  return (u16)(u >> 16);
}

#define MFMA(a, b, c) __builtin_amdgcn_mfma_f32_16x16x32_bf16((a), (b), (c), 0, 0, 0)

// ---------------- K0: convert weights fp32 -> bf16 ----------------
__global__ void __launch_bounds__(256) convw_kernel(
    const float* __restrict__ Wv, const float* __restrict__ Wk,
    const float* __restrict__ Wq, const float* __restrict__ Wo,
    u16* __restrict__ Wvb, u16* __restrict__ Wkb,
    u16* __restrict__ Wqb, u16* __restrict__ Wob) {
  int i = blockIdx.x * 256 + threadIdx.x;   // quad index; grid covers exactly
  const float* s; u16* d; int j;
  if (i < 262144) { s = Wo; d = Wob; j = i; }
  else {
    j = i - 262144;
    if (j < 1024)      { s = Wv; d = Wvb; }
    else if (j < 2048) { s = Wk; d = Wkb; j -= 1024; }
    else               { s = Wq; d = Wqb; j -= 2048; }
  }
  float4 f = ((const float4*)s)[j];
  ushort4 o; o.x = f2bf(f.x); o.y = f2bf(f.y); o.z = f2bf(f.z); o.w = f2bf(f.w);
  ((ushort4*)d)[j] = o;
}

// ---------------- K1: projections via MFMA ----------------
// grid = mat(3) x ns(16) x ttile(8) x h(16) = 6144 blocks.
// v output is stored TRANSPOSED: vpT[ns][h][d][l]  (PV B-operand layout)
__global__ void __launch_bounds__(256) proj_kernel(
    const float* __restrict__ vals, const float* __restrict__ keys,
    const float* __restrict__ qry,
    const u16* __restrict__ Wvb, const u16* __restrict__ Wkb,
    const u16* __restrict__ Wqb,
    u16* __restrict__ vpT, u16* __restrict__ kp, u16* __restrict__ qp) {
  const int b = blockIdx.x;
  const int h = b & 15, tt = (b >> 4) & 7, ns = (b >> 7) & 15, mat = b >> 11;
  const int tid = threadIdx.x;
  const float* src = (mat == 0 ? vals : mat == 1 ? keys : qry);
  const u16*   W   = (mat == 0 ? Wvb  : mat == 1 ? Wkb  : Wqb);
  __shared__ u16 xt[64][72];
  for (int i = tid; i < 1024; i += 256) {
    int t = i >> 4, dq = (i & 15) * 4;
    float4 f = *(const float4*)&src[((size_t)(ns*LL + tt*64 + t))*EE + h*DD + dq];
    ushort4 o; o.x = f2bf(f.x); o.y = f2bf(f.y); o.z = f2bf(f.z); o.w = f2bf(f.w);
    *(ushort4*)&xt[t][dq] = o;
  }
  __syncthreads();
  const int wid = tid >> 6, lane = tid & 63, quad = lane >> 4, l16 = lane & 15;
  bf16x8 a0 = *(const bf16x8*)&xt[wid*16 + l16][quad*8];
  bf16x8 a1 = *(const bf16x8*)&xt[wid*16 + l16][32 + quad*8];
  f32x4 z = {0.f, 0.f, 0.f, 0.f};
  f32x4 acc[4];
  #pragma unroll
  for (int nt = 0; nt < 4; ++nt) {
    bf16x8 b0 = *(const bf16x8*)&W[(nt*16 + l16)*DD + quad*8];
    bf16x8 b1 = *(const bf16x8*)&W[(nt*16 + l16)*DD + 32 + quad*8];
    acc[nt] = MFMA(a0, b0, z);
    acc[nt] = MFMA(a1, b1, acc[nt]);
  }
  if (mat == 0) {
    // transposed store: 4 consecutive tokens (r) at fixed d -> ushort4
    #pragma unroll
    for (int nt = 0; nt < 4; ++nt) {
      ushort4 o;
      o.x = f2bf(acc[nt][0]); o.y = f2bf(acc[nt][1]);
      o.z = f2bf(acc[nt][2]); o.w = f2bf(acc[nt][3]);
      size_t idx = ((size_t)((ns*HH + h)*DD + nt*16 + l16))*LL + tt*64 + wid*16 + quad*4;
      *(ushort4*)&vpT[idx] = o;
    }
  } else {
    u16* dst = (mat == 1 ? kp : qp);
    const int t0 = ns*LL + tt*64 + wid*16 + quad*4;
    #pragma unroll
    for (int nt = 0; nt < 4; ++nt)
      #pragma unroll
      for (int r = 0; r < 4; ++r)
        dst[(size_t)(t0 + r)*EE + h*DD + nt*16 + l16] = f2bf(acc[nt][r]);
  }
}

// ---------------- K2: per-column softmax denominator (softmax over q axis) ----
// grid = ns(16) x h(16) x ltile(8 of 64 l) = 2048 blocks. No LDS, no barriers.
// No max subtraction: logits = e/sqrt(512), |logit| < ~3, exp is safe.
__global__ void __launch_bounds__(256) colstats_kernel(
    const u16* __restrict__ qp, const u16* __restrict__ kp,
    const int* __restrict__ mask, float* __restrict__ colsi) {
  const int b = blockIdx.x;
  const int lt = b & 7, h = (b >> 3) & 15, ns = b >> 7;
  const int tid = threadIdx.x;
  const int wid = tid >> 6, lane = tid & 63, quad = lane >> 4, l16 = lane & 15;
  const int row_l = ns*LL + lt*64 + wid*16 + l16;
  bf16x8 kb0 = *(const bf16x8*)&kp[(size_t)row_l*EE + h*DD + quad*8];
  bf16x8 kb1 = *(const bf16x8*)&kp[(size_t)row_l*EE + h*DD + 32 + quad*8];
  f32x4 z = {0.f, 0.f, 0.f, 0.f};
  const int* mrow = mask + ns*LL;
  const u16* qbase = qp + (size_t)(ns*LL)*EE + h*DD;
  float s = 0.f;
  #pragma unroll 2
  for (int q0 = 0; q0 < LL; q0 += 16) {
    bf16x8 a0 = *(const bf16x8*)&qbase[(size_t)(q0 + l16)*EE + quad*8];
    bf16x8 a1 = *(const bf16x8*)&qbase[(size_t)(q0 + l16)*EE + 32 + quad*8];
    f32x4 e = MFMA(a0, kb0, z);
    e = MFMA(a1, kb1, e);
    #pragma unroll
    for (int r = 0; r < 4; ++r) {
      float mf = mrow[q0 + quad*4 + r] ? 1.f : 0.f;
      s += mf * __expf(e[r] * INV_SQRT_L);
    }
  }
  s += __shfl_xor(s, 16);
  s += __shfl_xor(s, 32);
  if (quad == 0) {
    if (!(s > 0.f)) s = 1.f;
    colsi[(ns*HH + h)*LL + lt*64 + wid*16 + l16] = 1.f / s;
  }
}

// ---------------- K3: recompute E, apply weights, PV -- all MFMA --------------
// grid = ns(16) x h(16) x qtile(8 of 64 q) = 2048 blocks.
// Only LDS use: per-wave P transpose (C-layout -> A-layout), no barriers in loop.
__global__ void __launch_bounds__(256) attnout_kernel(
    const u16* __restrict__ qp, const u16* __restrict__ kp,
    const u16* __restrict__ vpT, const int* __restrict__ mask,
    const float* __restrict__ colsi, u16* __restrict__ oat) {
  const int b = blockIdx.x;
  const int qt = b & 7, h = (b >> 3) & 15, ns = b >> 7;
  const int tid = threadIdx.x;
  const int wid = tid >> 6, lane = tid & 63, quad = lane >> 4, l16 = lane & 15;
  __shared__ u16 pt[4][16][72];
  // persistent Q fragments (16 q rows per wave)
  const int qrow = ns*LL + qt*64 + wid*16 + l16;
  bf16x8 qa0 = *(const bf16x8*)&qp[(size_t)qrow*EE + h*DD + quad*8];
  bf16x8 qa1 = *(const bf16x8*)&qp[(size_t)qrow*EE + h*DD + 32 + quad*8];
  float mqf[4];
  #pragma unroll
  for (int r = 0; r < 4; ++r)
    mqf[r] = mask[ns*LL + qt*64 + wid*16 + quad*4 + r] ? 1.f : 0.f;
  f32x4 z = {0.f, 0.f, 0.f, 0.f};
  f32x4 acc[4] = {z, z, z, z};
  const u16* kbase = kp + (size_t)(ns*LL)*EE + h*DD;
  const u16* vbase = vpT + (size_t)((ns*HH + h)*DD)*LL;
  const float* sbase = colsi + (ns*HH + h)*LL;
  for (int lc = 0; lc < 8; ++lc) {
    // E tiles: 16 q x 64 l
    f32x4 e[4];
    #pragma unroll
    for (int nt = 0; nt < 4; ++nt) {
      const u16* krow = kbase + (size_t)(lc*64 + nt*16 + l16)*EE;
      bf16x8 kb0 = *(const bf16x8*)&krow[quad*8];
      bf16x8 kb1 = *(const bf16x8*)&krow[32 + quad*8];
      e[nt] = MFMA(qa0, kb0, z);
      e[nt] = MFMA(qa1, kb1, e[nt]);
    }
    // P = mq * exp(e*scale) * colsinv  -> LDS transpose (per-wave private)
    #pragma unroll
    for (int nt = 0; nt < 4; ++nt) {
      float si = sbase[lc*64 + nt*16 + l16];
      #pragma unroll
      for (int r = 0; r < 4; ++r) {
        float a = mqf[r] * __expf(e[nt][r] * INV_SQRT_L) * si;
        pt[wid][quad*4 + r][nt*16 + l16] = f2bf(a);
      }
    }
    bf16x8 pa0 = *(const bf16x8*)&pt[wid][l16][quad*8];
    bf16x8 pa1 = *(const bf16x8*)&pt[wid][l16][32 + quad*8];
    // PV: out[16q x 64d] += P[16q x 64l] * V[64l x 64d]
    #pragma unroll
    for (int nt = 0; nt < 4; ++nt) {
      const u16* vrow = vbase + (size_t)(nt*16 + l16)*LL + lc*64;
      bf16x8 vb0 = *(const bf16x8*)&vrow[quad*8];
      bf16x8 vb1 = *(const bf16x8*)&vrow[32 + quad*8];
      acc[nt] = MFMA(pa0, vb0, acc[nt]);
      acc[nt] = MFMA(pa1, vb1, acc[nt]);
    }
  }
  const int t0 = ns*LL + qt*64 + wid*16 + quad*4;
  #pragma unroll
  for (int nt = 0; nt < 4; ++nt)
    #pragma unroll
    for (int r = 0; r < 4; ++r)
      oat[(size_t)(t0 + r)*EE + h*DD + nt*16 + l16] = f2bf(acc[nt][r]);
}

// ---------------- K4: Y = oat @ Wo^T + bo via MFMA ----------------
// grid = Mtiles(64 of 128) x Ntiles(16 of 64) = 1024 blocks; no LDS.
__global__ void __launch_bounds__(256) out_gemm_kernel(
    const u16* __restrict__ A, const u16* __restrict__ Wob,
    const float* __restrict__ bo, float* __restrict__ Y) {
  const int b = blockIdx.x;
  const int nb = b & 15, mb = b >> 4;
  const int tid = threadIdx.x;
  const int wid = tid >> 6, lane = tid & 63, quad = lane >> 4, l16 = lane & 15;
  f32x4 z = {0.f, 0.f, 0.f, 0.f};
  f32x4 acc[2][4] = {{z, z, z, z}, {z, z, z, z}};
  for (int k0 = 0; k0 < EE; k0 += 64) {
    bf16x8 a[2][2];
    #pragma unroll
    for (int ms = 0; ms < 2; ++ms) {
      const u16* arow = A + (size_t)(mb*128 + wid*32 + ms*16 + l16)*EE + k0;
      a[ms][0] = *(const bf16x8*)&arow[quad*8];
      a[ms][1] = *(const bf16x8*)&arow[32 + quad*8];
    }
    #pragma unroll
    for (int nt = 0; nt < 4; ++nt) {
      const u16* brow = Wob + (size_t)(nb*64 + nt*16 + l16)*EE + k0;
      bf16x8 b0 = *(const bf16x8*)&brow[quad*8];
      bf16x8 b1 = *(const bf16x8*)&brow[32 + quad*8];
      #pragma unroll
      for (int ms = 0; ms < 2; ++ms) {
        acc[ms][nt] = MFMA(a[ms][0], b0, acc[ms][nt]);
        acc[ms][nt] = MFMA(a[ms][1], b1, acc[ms][nt]);
      }
    }
  }
  #pragma unroll
  for (int ms = 0; ms < 2; ++ms)
    #pragma unroll
    for (int nt = 0; nt < 4; ++nt) {
      int col = nb*64 + nt*16 + l16;
      float bias = bo[col];
      #pragma unroll
      for (int r = 0; r < 4; ++r)
        Y[(size_t)(mb*128 + wid*32 + ms*16 + quad*4 + r)*EE + col] = acc[ms][nt][r] + bias;
    }
}

extern "C" void kernel_launch(void* const* d_in, const int* in_sizes, int n_in,
                              void* d_out, int out_size, void* d_ws, size_t ws_size,
                              hipStream_t stream) {
  const float* values = (const float*)d_in[0];
  const float* keysp  = (const float*)d_in[1];
  const float* query  = (const float*)d_in[2];
  const int*   mask   = (const int*)d_in[3];
  const float* Wv = (const float*)d_in[4];
  const float* Wk = (const float*)d_in[5];
  const float* Wq = (const float*)d_in[6];
  const float* Wo = (const float*)d_in[7];
  const float* bo = (const float*)d_in[8];
  float* Y = (float*)d_out;

  // workspace layout (u16 units unless noted)
  u16* qp  = (u16*)d_ws;
  u16* kp  = qp + NSLE;
  u16* vpT = kp + NSLE;
  u16* oat = vpT + NSLE;
  u16* Wob = oat + NSLE;
  u16* Wvb = Wob + EE*EE;
  u16* Wkb = Wvb + DD*DD;
  u16* Wqb = Wkb + DD*DD;
  float* colsi = (float*)(Wqb + DD*DD);

  convw_kernel<<<1036, 256, 0, stream>>>(Wv, Wk, Wq, Wo, Wvb, Wkb, Wqb, Wob);
  proj_kernel<<<3*NSX*HH*(LL/64), 256, 0, stream>>>(values, keysp, query,
                                                    Wvb, Wkb, Wqb, vpT, kp, qp);
  colstats_kernel<<<NSX*HH*(LL/64), 256, 0, stream>>>(qp, kp, mask, colsi);
  attnout_kernel<<<NSX*HH*(LL/64), 256, 0, stream>>>(qp, kp, vpT, mask, colsi, oat);
  out_gemm_kernel<<<(NT/128)*(EE/64), 256, 0, stream>>>(oat, Wob, bo, Y);
}

// Round 6
// 338.578 us; speedup vs baseline: 6.1654x; 1.3322x over previous
//
#include <hip/hip_runtime.h>
#include <math.h>

#define LL 512
#define EE 1024
#define HH 16
#define DD 64
#define NSX 16               // N*S
#define NT (NSX*LL)          // 8192 tokens
#define NSLE (NT*EE)         // 8388608
// q is pre-scaled by (1/sqrt(512)) * log2(e) so softmax uses native exp2
#define SCALE_Q 0.06375871f

typedef unsigned short u16;
typedef short bf16x8 __attribute__((ext_vector_type(8)));
typedef float f32x4 __attribute__((ext_vector_type(4)));

__device__ inline u16 f2bf(float f) {
  unsigned u = __float_as_uint(f);
  u += 0x7fff + ((u >> 16) & 1);          // RNE
  return (u16)(u >> 16);
}

// direct builtin calls only; ONLY gfx950-verified MFMA shapes (16x16x32)
#define FEXP2(x) __builtin_amdgcn_exp2f(x)
#define MFMA32(a, b, c) __builtin_amdgcn_mfma_f32_16x16x32_bf16((a), (b), (c), 0, 0, 0)

// ---------------- K0: convert weights fp32 -> bf16 ----------------
__global__ void __launch_bounds__(256) convw_kernel(
    const float* __restrict__ Wv, const float* __restrict__ Wk,
    const float* __restrict__ Wq, const float* __restrict__ Wo,
    u16* __restrict__ Wvb, u16* __restrict__ Wkb,
    u16* __restrict__ Wqb, u16* __restrict__ Wob) {
  int i = blockIdx.x * 256 + threadIdx.x;   // quad index
  const float* s; u16* d; int j;
  if (i < 262144) { s = Wo; d = Wob; j = i; }
  else {
    j = i - 262144;
    if (j < 1024)      { s = Wv; d = Wvb; }
    else if (j < 2048) { s = Wk; d = Wkb; j -= 1024; }
    else               { s = Wq; d = Wqb; j -= 2048; }
  }
  float4 f = ((const float4*)s)[j];
  ushort4 o; o.x = f2bf(f.x); o.y = f2bf(f.y); o.z = f2bf(f.z); o.w = f2bf(f.w);
  ((ushort4*)d)[j] = o;
}

// ---------------- K1: projections via MFMA (round-3-proven structure) --------
// grid = mat(3) x ns(16) x ttile(8) x h(16) = 6144 blocks.
// v stored TRANSPOSED vpT[ns][h][d][l]; k,q token-major (q pre-scaled by SCALE_Q)
__global__ void __launch_bounds__(256) proj_kernel(
    const float* __restrict__ vals, const float* __restrict__ keys,
    const float* __restrict__ qry,
    const u16* __restrict__ Wvb, const u16* __restrict__ Wkb,
    const u16* __restrict__ Wqb,
    u16* __restrict__ vpT, u16* __restrict__ kp, u16* __restrict__ qp) {
  const int b = blockIdx.x;
  const int h = b & 15, tt = (b >> 4) & 7, ns = (b >> 7) & 15, mat = b >> 11;
  const int tid = threadIdx.x;
  const float* src = (mat == 0 ? vals : mat == 1 ? keys : qry);
  const u16*   W   = (mat == 0 ? Wvb  : mat == 1 ? Wkb  : Wqb);
  __shared__ u16 xt[64][72];
  for (int i = tid; i < 1024; i += 256) {
    int t = i >> 4, dq = (i & 15) * 4;
    float4 f = *(const float4*)&src[((size_t)(ns*LL + tt*64 + t))*EE + h*DD + dq];
    ushort4 o; o.x = f2bf(f.x); o.y = f2bf(f.y); o.z = f2bf(f.z); o.w = f2bf(f.w);
    *(ushort4*)&xt[t][dq] = o;
  }
  __syncthreads();
  const int wid = tid >> 6, lane = tid & 63, quad = lane >> 4, l16 = lane & 15;
  bf16x8 a0 = *(const bf16x8*)&xt[wid*16 + l16][quad*8];
  bf16x8 a1 = *(const bf16x8*)&xt[wid*16 + l16][32 + quad*8];
  f32x4 z = {0.f, 0.f, 0.f, 0.f};
  f32x4 acc[4];
  #pragma unroll
  for (int nt = 0; nt < 4; ++nt) {
    bf16x8 b0 = *(const bf16x8*)&W[(nt*16 + l16)*DD + quad*8];
    bf16x8 b1 = *(const bf16x8*)&W[(nt*16 + l16)*DD + 32 + quad*8];
    acc[nt] = MFMA32(a0, b0, z);
    acc[nt] = MFMA32(a1, b1, acc[nt]);
  }
  if (mat == 0) {
    // transposed store: 4 consecutive tokens at fixed d
    #pragma unroll
    for (int nt = 0; nt < 4; ++nt) {
      ushort4 o;
      o.x = f2bf(acc[nt][0]); o.y = f2bf(acc[nt][1]);
      o.z = f2bf(acc[nt][2]); o.w = f2bf(acc[nt][3]);
      size_t idx = ((size_t)((ns*HH + h)*DD + nt*16 + l16))*LL + tt*64 + wid*16 + quad*4;
      *(ushort4*)&vpT[idx] = o;
    }
  } else {
    u16* dst = (mat == 1 ? kp : qp);
    const float sc = (mat == 2) ? SCALE_Q : 1.f;
    const int t0 = ns*LL + tt*64 + wid*16 + quad*4;
    #pragma unroll
    for (int nt = 0; nt < 4; ++nt)
      #pragma unroll
      for (int r = 0; r < 4; ++r)
        dst[(size_t)(t0 + r)*EE + h*DD + nt*16 + l16] = f2bf(acc[nt][r] * sc);
  }
}

// ---------------- K2: fused column-softmax + attention-out ----------------
// one block per (ns,h): 256 blocks x 1024 threads. K resident in LDS; V chunk
// double-buffered; P via per-wave LDS transpose (round-3-proven); MFMA32 only.
// softmax is over the QUERY axis: colsum_l = sum_q mask_q * exp2(e_ql).
__global__ void __launch_bounds__(1024, 4) attn_kernel(
    const u16* __restrict__ qp, const u16* __restrict__ kp,
    const u16* __restrict__ vpT, const int* __restrict__ mask,
    u16* __restrict__ oat) {
  const int b = blockIdx.x;
  const int h = b & 15, ns = b >> 4;
  const int tid = threadIdx.x;
  const int wid = tid >> 6, lane = tid & 63, quad = lane >> 4, l16 = lane & 15;
  __shared__ u16 Ks[LL][72];        // K[l][d]      73728 B (stride 36 words: ideal)
  __shared__ u16 Vt[2][DD][72];     // V^T[d][l64]  18432 B
  __shared__ u16 pt[16][32][40];    // per-wave P   40960 B (stride 20 words: ideal)
  __shared__ float csum[LL];        //               2048 B   => 135168 B total
  // ---- stage K; zero csum ----
  const size_t kgbase = ((size_t)(ns*LL))*EE + h*DD;
  for (int i = tid; i < 4096; i += 1024) {          // 512 rows x 8 segs of 16B
    int row = i >> 3, seg = (i & 7) * 8;
    *(bf16x8*)&Ks[row][seg] = *(const bf16x8*)&kp[kgbase + (size_t)row*EE + seg];
  }
  if (tid < LL) csum[tid] = 0.f;
  // ---- persistent Q fragments (wave owns 32 q rows) + masks ----
  const int q0 = wid*32;
  bf16x8 qf[2][2];
  float maf[2][4];
  #pragma unroll
  for (int qt = 0; qt < 2; ++qt) {
    const u16* qrow = qp + ((size_t)(ns*LL + q0 + qt*16 + l16))*EE + h*DD;
    qf[qt][0] = *(const bf16x8*)&qrow[quad*8];
    qf[qt][1] = *(const bf16x8*)&qrow[32 + quad*8];
    #pragma unroll
    for (int r = 0; r < 4; ++r)
      maf[qt][r] = mask[ns*LL + q0 + qt*16 + quad*4 + r] ? 1.f : 0.f;
  }
  f32x4 z = {0.f, 0.f, 0.f, 0.f};
  __syncthreads();
  // ---- phase A: column sums.  E tile: A=Q(m=q), B=K(n=l) -> D[q][l] ----
  for (int lt = 0; lt < 32; ++lt) {
    bf16x8 kf0 = *(const bf16x8*)&Ks[lt*16 + l16][quad*8];
    bf16x8 kf1 = *(const bf16x8*)&Ks[lt*16 + l16][32 + quad*8];
    float part = 0.f;
    #pragma unroll
    for (int qt = 0; qt < 2; ++qt) {
      f32x4 e = MFMA32(qf[qt][0], kf0, z);
      e = MFMA32(qf[qt][1], kf1, e);
      #pragma unroll
      for (int r = 0; r < 4; ++r)
        part += maf[qt][r] * FEXP2(e[r]);     // e row = q(quad*4+r), col = l(l16)
    }
    atomicAdd(&csum[lt*16 + l16], part);
  }
  __syncthreads();
  if (tid < LL) { float s = csum[tid]; csum[tid] = (s > 0.f) ? 1.f/s : 0.f; }
  __syncthreads();
  // ---- phase B: E recompute -> P (LDS transpose) -> PV, V chunks of 64 l ----
  f32x4 acc[4][2] = {{z,z},{z,z},{z,z},{z,z}};   // [dtile][qt]
  const size_t vgbase = ((size_t)((ns*HH + h)*DD))*LL;
  for (int lc = 0; lc < 8; ++lc) {               // 8 chunks of 64 l
    if (tid < 512) {                             // stage V^T[d][lc*64..+63]
      int row = tid >> 3, seg = (tid & 7) * 8;
      *(bf16x8*)&Vt[lc & 1][row][seg] =
          *(const bf16x8*)&vpT[vgbase + (size_t)row*LL + lc*64 + seg];
    }
    __syncthreads();                             // one barrier per chunk (dbuf)
    // E + P for 64 l in 4 sub-tiles of 16
    #pragma unroll
    for (int lt2 = 0; lt2 < 4; ++lt2) {
      const int lrow = lc*64 + lt2*16 + l16;
      bf16x8 kf0 = *(const bf16x8*)&Ks[lrow][quad*8];
      bf16x8 kf1 = *(const bf16x8*)&Ks[lrow][32 + quad*8];
      const float csv = csum[lrow];
      #pragma unroll
      for (int qt = 0; qt < 2; ++qt) {
        f32x4 e = MFMA32(qf[qt][0], kf0, z);
        e = MFMA32(qf[qt][1], kf1, e);
        #pragma unroll
        for (int r = 0; r < 4; ++r)
          pt[wid][qt*16 + quad*4 + r][lt2 & 1 ? 16 + l16 : l16] =
              f2bf(maf[qt][r] * csv * FEXP2(e[r]));
        // PV for the 32-l half once both sub-tiles of it are in pt
        if (lt2 & 1) {
          bf16x8 pa = *(const bf16x8*)&pt[wid][qt*16 + l16][quad*8];
          #pragma unroll
          for (int dt = 0; dt < 4; ++dt) {
            bf16x8 vb = *(const bf16x8*)&Vt[lc & 1][dt*16 + l16]
                                        [(lt2 >> 1)*32 + quad*8];
            acc[dt][qt] = MFMA32(pa, vb, acc[dt][qt]);
          }
        }
      }
    }
  }
  // ---- write out[q][d]: D row = q(quad*4+r), col = d(l16) ----
  #pragma unroll
  for (int qt = 0; qt < 2; ++qt)
    #pragma unroll
    for (int dt = 0; dt < 4; ++dt)
      #pragma unroll
      for (int r = 0; r < 4; ++r)
        oat[((size_t)(ns*LL + q0 + qt*16 + quad*4 + r))*EE + h*DD + dt*16 + l16] =
            f2bf(acc[dt][qt][r]);
}

// ---------------- K4: Y = oat @ Wo^T + bo via MFMA ----------------
__global__ void __launch_bounds__(256) out_gemm_kernel(
    const u16* __restrict__ A, const u16* __restrict__ Wob,
    const float* __restrict__ bo, float* __restrict__ Y) {
  const int b = blockIdx.x;
  const int nb = b & 15, mb = b >> 4;
  const int tid = threadIdx.x;
  const int wid = tid >> 6, lane = tid & 63, quad = lane >> 4, l16 = lane & 15;
  f32x4 z = {0.f, 0.f, 0.f, 0.f};
  f32x4 acc[2][4] = {{z, z, z, z}, {z, z, z, z}};
  for (int k0 = 0; k0 < EE; k0 += 64) {
    bf16x8 a[2][2];
    #pragma unroll
    for (int ms = 0; ms < 2; ++ms) {
      const u16* arow = A + (size_t)(mb*128 + wid*32 + ms*16 + l16)*EE + k0;
      a[ms][0] = *(const bf16x8*)&arow[quad*8];
      a[ms][1] = *(const bf16x8*)&arow[32 + quad*8];
    }
    #pragma unroll
    for (int nt = 0; nt < 4; ++nt) {
      const u16* brow = Wob + (size_t)(nb*64 + nt*16 + l16)*EE + k0;
      bf16x8 b0 = *(const bf16x8*)&brow[quad*8];
      bf16x8 b1 = *(const bf16x8*)&brow[32 + quad*8];
      #pragma unroll
      for (int ms = 0; ms < 2; ++ms) {
        acc[ms][nt] = MFMA32(a[ms][0], b0, acc[ms][nt]);
        acc[ms][nt] = MFMA32(a[ms][1], b1, acc[ms][nt]);
      }
    }
  }
  #pragma unroll
  for (int ms = 0; ms < 2; ++ms)
    #pragma unroll
    for (int nt = 0; nt < 4; ++nt) {
      int col = nb*64 + nt*16 + l16;
      float bias = bo[col];
      #pragma unroll
      for (int r = 0; r < 4; ++r)
        Y[(size_t)(mb*128 + wid*32 + ms*16 + quad*4 + r)*EE + col] = acc[ms][nt][r] + bias;
    }
}

extern "C" void kernel_launch(void* const* d_in, const int* in_sizes, int n_in,
                              void* d_out, int out_size, void* d_ws, size_t ws_size,
                              hipStream_t stream) {
  const float* values = (const float*)d_in[0];
  const float* keysp  = (const float*)d_in[1];
  const float* query  = (const float*)d_in[2];
  const int*   mask   = (const int*)d_in[3];
  const float* Wv = (const float*)d_in[4];
  const float* Wk = (const float*)d_in[5];
  const float* Wq = (const float*)d_in[6];
  const float* Wo = (const float*)d_in[7];
  const float* bo = (const float*)d_in[8];
  float* Y = (float*)d_out;

  u16* qp  = (u16*)d_ws;
  u16* kp  = qp + NSLE;
  u16* vpT = kp + NSLE;
  u16* oat = vpT + NSLE;
  u16* Wob = oat + NSLE;
  u16* Wvb = Wob + EE*EE;
  u16* Wkb = Wvb + DD*DD;
  u16* Wqb = Wkb + DD*DD;

  convw_kernel<<<1036, 256, 0, stream>>>(Wv, Wk, Wq, Wo, Wvb, Wkb, Wqb, Wob);
  proj_kernel<<<3*NSX*HH*(LL/64), 256, 0, stream>>>(values, keysp, query,
                                                    Wvb, Wkb, Wqb, vpT, kp, qp);
  attn_kernel<<<NSX*HH, 1024, 0, stream>>>(qp, kp, vpT, mask, oat);
  out_gemm_kernel<<<(NT/128)*(EE/64), 256, 0, stream>>>(oat, Wob, bo, Y);
}

// Round 7
// 236.385 us; speedup vs baseline: 8.8308x; 1.4323x over previous
//
#include <hip/hip_runtime.h>
#include <math.h>

#define LL 512
#define EE 1024
#define HH 16
#define DD 64
#define NSX 16               // N*S
#define NT (NSX*LL)          // 8192 tokens
#define NSLE (NT*EE)         // 8388608
// q is pre-scaled by (1/sqrt(512)) * log2(e) so softmax uses native exp2
#define SCALE_Q 0.06375871f

typedef unsigned short u16;
typedef short bf16x8 __attribute__((ext_vector_type(8)));
typedef float f32x4 __attribute__((ext_vector_type(4)));

__device__ inline u16 f2bf(float f) {
  unsigned u = __float_as_uint(f);
  u += 0x7fff + ((u >> 16) & 1);          // RNE
  return (u16)(u >> 16);
}

// direct builtin calls only; ONLY gfx950-verified MFMA shapes (16x16x32)
#define FEXP2(x) __builtin_amdgcn_exp2f(x)
#define MFMA32(a, b, c) __builtin_amdgcn_mfma_f32_16x16x32_bf16((a), (b), (c), 0, 0, 0)

// ---------------- K0: convert weights fp32 -> bf16 ----------------
__global__ void __launch_bounds__(256) convw_kernel(
    const float* __restrict__ Wv, const float* __restrict__ Wk,
    const float* __restrict__ Wq, const float* __restrict__ Wo,
    u16* __restrict__ Wvb, u16* __restrict__ Wkb,
    u16* __restrict__ Wqb, u16* __restrict__ Wob) {
  int i = blockIdx.x * 256 + threadIdx.x;   // quad index
  const float* s; u16* d; int j;
  if (i < 262144) { s = Wo; d = Wob; j = i; }
  else {
    j = i - 262144;
    if (j < 1024)      { s = Wv; d = Wvb; }
    else if (j < 2048) { s = Wk; d = Wkb; j -= 1024; }
    else               { s = Wq; d = Wqb; j -= 2048; }
  }
  float4 f = ((const float4*)s)[j];
  ushort4 o; o.x = f2bf(f.x); o.y = f2bf(f.y); o.z = f2bf(f.z); o.w = f2bf(f.w);
  ((ushort4*)d)[j] = o;
}

// ---------------- K1: projections via MFMA ----------------
// grid = mat(3) x ns(16) x ttile(8) x h(16) = 6144 blocks.
// v stored TRANSPOSED vpT[ns][h][d][l]; k,q token-major (q pre-scaled),
// k/q stores coalesced via LDS transpose.
__global__ void __launch_bounds__(256) proj_kernel(
    const float* __restrict__ vals, const float* __restrict__ keys,
    const float* __restrict__ qry,
    const u16* __restrict__ Wvb, const u16* __restrict__ Wkb,
    const u16* __restrict__ Wqb,
    u16* __restrict__ vpT, u16* __restrict__ kp, u16* __restrict__ qp) {
  const int b = blockIdx.x;
  const int h = b & 15, tt = (b >> 4) & 7, ns = (b >> 7) & 15, mat = b >> 11;
  const int tid = threadIdx.x;
  const float* src = (mat == 0 ? vals : mat == 1 ? keys : qry);
  const u16*   W   = (mat == 0 ? Wvb  : mat == 1 ? Wkb  : Wqb);
  __shared__ u16 xt[64][72];
  for (int i = tid; i < 1024; i += 256) {
    int t = i >> 4, dq = (i & 15) * 4;
    float4 f = *(const float4*)&src[((size_t)(ns*LL + tt*64 + t))*EE + h*DD + dq];
    ushort4 o; o.x = f2bf(f.x); o.y = f2bf(f.y); o.z = f2bf(f.z); o.w = f2bf(f.w);
    *(ushort4*)&xt[t][dq] = o;
  }
  __syncthreads();
  const int wid = tid >> 6, lane = tid & 63, quad = lane >> 4, l16 = lane & 15;
  bf16x8 a0 = *(const bf16x8*)&xt[wid*16 + l16][quad*8];
  bf16x8 a1 = *(const bf16x8*)&xt[wid*16 + l16][32 + quad*8];
  f32x4 z = {0.f, 0.f, 0.f, 0.f};
  f32x4 acc[4];
  #pragma unroll
  for (int nt = 0; nt < 4; ++nt) {
    bf16x8 b0 = *(const bf16x8*)&W[(nt*16 + l16)*DD + quad*8];
    bf16x8 b1 = *(const bf16x8*)&W[(nt*16 + l16)*DD + 32 + quad*8];
    acc[nt] = MFMA32(a0, b0, z);
    acc[nt] = MFMA32(a1, b1, acc[nt]);
  }
  if (mat == 0) {
    // transposed store: 4 consecutive tokens at fixed d
    #pragma unroll
    for (int nt = 0; nt < 4; ++nt) {
      ushort4 o;
      o.x = f2bf(acc[nt][0]); o.y = f2bf(acc[nt][1]);
      o.z = f2bf(acc[nt][2]); o.w = f2bf(acc[nt][3]);
      size_t idx = ((size_t)((ns*HH + h)*DD + nt*16 + l16))*LL + tt*64 + wid*16 + quad*4;
      *(ushort4*)&vpT[idx] = o;
    }
  } else {
    u16* dst = (mat == 1 ? kp : qp);
    const float sc = (mat == 2) ? SCALE_Q : 1.f;
    __syncthreads();                       // all frag reads of xt done
    #pragma unroll
    for (int nt = 0; nt < 4; ++nt)
      #pragma unroll
      for (int r = 0; r < 4; ++r)
        xt[wid*16 + quad*4 + r][nt*16 + l16] = f2bf(acc[nt][r] * sc);
    __syncthreads();
    for (int i = tid; i < 512; i += 256) {  // 64 rows x 8 segs of 16B
      int row = i >> 3, seg = (i & 7) * 8;
      *(bf16x8*)&dst[((size_t)(ns*LL + tt*64 + row))*EE + h*DD + seg] =
          *(const bf16x8*)&xt[row][seg];
    }
  }
}

// ---------------- K2: fused column-softmax + attention-out ----------------
// one block per (ns,h): 256 blocks x 1024 threads. K resident in LDS; V chunk
// double-buffered; P via per-wave LDS transpose; MFMA32 only.
// softmax is over the QUERY axis: colsum_l = sum_q mask_q * exp2(e_ql).
// phase A uses shfl-reduce + per-wave psum (reuses pt space) -- no LDS atomics.
__global__ void __launch_bounds__(1024, 4) attn_kernel(
    const u16* __restrict__ qp, const u16* __restrict__ kp,
    const u16* __restrict__ vpT, const int* __restrict__ mask,
    u16* __restrict__ oat) {
  const int b = blockIdx.x;
  const int h = b & 15, ns = b >> 4;
  const int tid = threadIdx.x;
  const int wid = tid >> 6, lane = tid & 63, quad = lane >> 4, l16 = lane & 15;
  __shared__ u16 Ks[LL][72];        // K[l][d]      73728 B
  __shared__ u16 Vt[2][DD][72];     // V^T[d][l64]  18432 B
  __shared__ u16 pt[16][32][40];    // per-wave P   40960 B (phase A: psum f32[16][512])
  __shared__ float csum[LL];        //               2048 B   => 135168 B total
  float* psum = (float*)pt;
  // ---- stage K ----
  const size_t kgbase = ((size_t)(ns*LL))*EE + h*DD;
  for (int i = tid; i < 4096; i += 1024) {          // 512 rows x 8 segs of 16B
    int row = i >> 3, seg = (i & 7) * 8;
    *(bf16x8*)&Ks[row][seg] = *(const bf16x8*)&kp[kgbase + (size_t)row*EE + seg];
  }
  // ---- persistent Q fragments (wave owns 32 q rows) + masks ----
  const int q0 = wid*32;
  bf16x8 qf[2][2];
  float maf[2][4];
  #pragma unroll
  for (int qt = 0; qt < 2; ++qt) {
    const u16* qrow = qp + ((size_t)(ns*LL + q0 + qt*16 + l16))*EE + h*DD;
    qf[qt][0] = *(const bf16x8*)&qrow[quad*8];
    qf[qt][1] = *(const bf16x8*)&qrow[32 + quad*8];
    #pragma unroll
    for (int r = 0; r < 4; ++r)
      maf[qt][r] = mask[ns*LL + q0 + qt*16 + quad*4 + r] ? 1.f : 0.f;
  }
  f32x4 z = {0.f, 0.f, 0.f, 0.f};
  __syncthreads();
  // ---- phase A: column partial sums -> psum[wid][l], then block reduce ----
  for (int lt = 0; lt < 32; ++lt) {
    bf16x8 kf0 = *(const bf16x8*)&Ks[lt*16 + l16][quad*8];
    bf16x8 kf1 = *(const bf16x8*)&Ks[lt*16 + l16][32 + quad*8];
    float part = 0.f;
    #pragma unroll
    for (int qt = 0; qt < 2; ++qt) {
      f32x4 e = MFMA32(qf[qt][0], kf0, z);
      e = MFMA32(qf[qt][1], kf1, e);
      #pragma unroll
      for (int r = 0; r < 4; ++r)
        part += maf[qt][r] * FEXP2(e[r]);     // e row = q(quad*4+r), col = l(l16)
    }
    part += __shfl_xor(part, 16);             // combine 4 quads (same l16)
    part += __shfl_xor(part, 32);
    if (quad == 0) psum[wid*512 + lt*16 + l16] = part;
  }
  __syncthreads();
  if (tid < LL) {
    float s = 0.f;
    #pragma unroll
    for (int w = 0; w < 16; ++w) s += psum[w*512 + tid];
    csum[tid] = (s > 0.f) ? 1.f/s : 0.f;
  }
  __syncthreads();
  // ---- phase B: E recompute -> P (LDS transpose) -> PV, V chunks of 64 l ----
  f32x4 acc[4][2] = {{z,z},{z,z},{z,z},{z,z}};   // [dtile][qt]
  const size_t vgbase = ((size_t)((ns*HH + h)*DD))*LL;
  for (int lc = 0; lc < 8; ++lc) {               // 8 chunks of 64 l
    if (tid < 512) {                             // stage V^T[d][lc*64..+63]
      int row = tid >> 3, seg = (tid & 7) * 8;
      *(bf16x8*)&Vt[lc & 1][row][seg] =
          *(const bf16x8*)&vpT[vgbase + (size_t)row*LL + lc*64 + seg];
    }
    __syncthreads();                             // one barrier per chunk (dbuf)
    // E + P for 64 l in 4 sub-tiles of 16
    #pragma unroll
    for (int lt2 = 0; lt2 < 4; ++lt2) {
      const int lrow = lc*64 + lt2*16 + l16;
      bf16x8 kf0 = *(const bf16x8*)&Ks[lrow][quad*8];
      bf16x8 kf1 = *(const bf16x8*)&Ks[lrow][32 + quad*8];
      const float csv = csum[lrow];
      #pragma unroll
      for (int qt = 0; qt < 2; ++qt) {
        f32x4 e = MFMA32(qf[qt][0], kf0, z);
        e = MFMA32(qf[qt][1], kf1, e);
        #pragma unroll
        for (int r = 0; r < 4; ++r)
          pt[wid][qt*16 + quad*4 + r][lt2 & 1 ? 16 + l16 : l16] =
              f2bf(maf[qt][r] * csv * FEXP2(e[r]));
        // PV for the 32-l half once both sub-tiles of it are in pt
        if (lt2 & 1) {
          bf16x8 pa = *(const bf16x8*)&pt[wid][qt*16 + l16][quad*8];
          #pragma unroll
          for (int dt = 0; dt < 4; ++dt) {
            bf16x8 vb = *(const bf16x8*)&Vt[lc & 1][dt*16 + l16]
                                        [(lt2 >> 1)*32 + quad*8];
            acc[dt][qt] = MFMA32(pa, vb, acc[dt][qt]);
          }
        }
      }
    }
  }
  // ---- write out[q][d]: D row = q(quad*4+r), col = d(l16) ----
  #pragma unroll
  for (int qt = 0; qt < 2; ++qt)
    #pragma unroll
    for (int dt = 0; dt < 4; ++dt)
      #pragma unroll
      for (int r = 0; r < 4; ++r)
        oat[((size_t)(ns*LL + q0 + qt*16 + quad*4 + r))*EE + h*DD + dt*16 + l16] =
            f2bf(acc[dt][qt][r]);
}

// ---------------- K4: Y = oat @ Wo^T + bo, LDS-tiled MFMA GEMM ----------------
// 128x128 tile, BK=64, 4 waves each computing a 64x64 quadrant.
__global__ void __launch_bounds__(256) out_gemm_kernel(
    const u16* __restrict__ A, const u16* __restrict__ Wob,
    const float* __restrict__ bo, float* __restrict__ Y) {
  __shared__ u16 As[128][72];   // [m][k]  18432 B (stride 36 words: 2-way, free)
  __shared__ u16 Bs[128][72];   // [n][k]  18432 B
  const int b = blockIdx.x;     // 64 mtiles x 8 ntiles
  const int nb = b & 7, mb = b >> 3;
  const int m0 = mb*128, n0 = nb*128;
  const int tid = threadIdx.x;
  const int wid = tid >> 6, lane = tid & 63, quad = lane >> 4, l16 = lane & 15;
  const int wm = (wid >> 1)*64, wn = (wid & 1)*64;   // wave quadrant
  f32x4 z = {0.f, 0.f, 0.f, 0.f};
  f32x4 acc[4][4];
  #pragma unroll
  for (int i = 0; i < 4; ++i)
    #pragma unroll
    for (int j = 0; j < 4; ++j) acc[i][j] = z;
  for (int k0 = 0; k0 < EE; k0 += 64) {
    __syncthreads();
    #pragma unroll
    for (int it = 0; it < 4; ++it) {      // stage 128 rows x 64 k each
      int idx = it*256 + tid;
      int row = idx >> 3, seg = (idx & 7) * 8;
      *(bf16x8*)&As[row][seg] = *(const bf16x8*)&A  [(size_t)(m0 + row)*EE + k0 + seg];
      *(bf16x8*)&Bs[row][seg] = *(const bf16x8*)&Wob[(size_t)(n0 + row)*EE + k0 + seg];
    }
    __syncthreads();
    #pragma unroll
    for (int kk = 0; kk < 2; ++kk) {
      bf16x8 af[4], bfr[4];
      #pragma unroll
      for (int i = 0; i < 4; ++i)
        af[i] = *(const bf16x8*)&As[wm + i*16 + l16][kk*32 + quad*8];
      #pragma unroll
      for (int j = 0; j < 4; ++j)
        bfr[j] = *(const bf16x8*)&Bs[wn + j*16 + l16][kk*32 + quad*8];
      #pragma unroll
      for (int i = 0; i < 4; ++i)
        #pragma unroll
        for (int j = 0; j < 4; ++j)
          acc[i][j] = MFMA32(af[i], bfr[j], acc[i][j]);
    }
  }
  #pragma unroll
  for (int i = 0; i < 4; ++i)
    #pragma unroll
    for (int j = 0; j < 4; ++j) {
      int col = n0 + wn + j*16 + l16;
      float bias = bo[col];
      #pragma unroll
      for (int r = 0; r < 4; ++r)
        Y[(size_t)(m0 + wm + i*16 + quad*4 + r)*EE + col] = acc[i][j][r] + bias;
    }
}

extern "C" void kernel_launch(void* const* d_in, const int* in_sizes, int n_in,
                              void* d_out, int out_size, void* d_ws, size_t ws_size,
                              hipStream_t stream) {
  const float* values = (const float*)d_in[0];
  const float* keysp  = (const float*)d_in[1];
  const float* query  = (const float*)d_in[2];
  const int*   mask   = (const int*)d_in[3];
  const float* Wv = (const float*)d_in[4];
  const float* Wk = (const float*)d_in[5];
  const float* Wq = (const float*)d_in[6];
  const float* Wo = (const float*)d_in[7];
  const float* bo = (const float*)d_in[8];
  float* Y = (float*)d_out;

  u16* qp  = (u16*)d_ws;
  u16* kp  = qp + NSLE;
  u16* vpT = kp + NSLE;
  u16* oat = vpT + NSLE;
  u16* Wob = oat + NSLE;
  u16* Wvb = Wob + EE*EE;
  u16* Wkb = Wvb + DD*DD;
  u16* Wqb = Wkb + DD*DD;

  convw_kernel<<<1036, 256, 0, stream>>>(Wv, Wk, Wq, Wo, Wvb, Wkb, Wqb, Wob);
  proj_kernel<<<3*NSX*HH*(LL/64), 256, 0, stream>>>(values, keysp, query,
                                                    Wvb, Wkb, Wqb, vpT, kp, qp);
  attn_kernel<<<NSX*HH, 1024, 0, stream>>>(qp, kp, vpT, mask, oat);
  out_gemm_kernel<<<(NT/128)*(EE/128), 256, 0, stream>>>(oat, Wob, bo, Y);
}

// Round 8
// 229.672 us; speedup vs baseline: 9.0889x; 1.0292x over previous
//
#include <hip/hip_runtime.h>
#include <math.h>

#define LL 512
#define EE 1024
#define HH 16
#define DD 64
#define NSX 16               // N*S
#define NT (NSX*LL)          // 8192 tokens
#define NSLE (NT*EE)         // 8388608
// q is pre-scaled by (1/sqrt(512)) * log2(e) so softmax uses native exp2
#define SCALE_Q 0.06375871f

typedef unsigned short u16;
typedef short bf16x8 __attribute__((ext_vector_type(8)));
typedef float f32x4 __attribute__((ext_vector_type(4)));

__device__ inline u16 f2bf(float f) {
  unsigned u = __float_as_uint(f);
  u += 0x7fff + ((u >> 16) & 1);          // RNE
  return (u16)(u >> 16);
}

// direct builtin calls only; ONLY gfx950-verified MFMA shapes (16x16x32)
#define FEXP2(x) __builtin_amdgcn_exp2f(x)
#define MFMA32(a, b, c) __builtin_amdgcn_mfma_f32_16x16x32_bf16((a), (b), (c), 0, 0, 0)

// ---------------- K0: convert weights fp32 -> bf16 ----------------
__global__ void __launch_bounds__(256) convw_kernel(
    const float* __restrict__ Wv, const float* __restrict__ Wk,
    const float* __restrict__ Wq, const float* __restrict__ Wo,
    u16* __restrict__ Wvb, u16* __restrict__ Wkb,
    u16* __restrict__ Wqb, u16* __restrict__ Wob) {
  int i = blockIdx.x * 256 + threadIdx.x;   // quad index
  const float* s; u16* d; int j;
  if (i < 262144) { s = Wo; d = Wob; j = i; }
  else {
    j = i - 262144;
    if (j < 1024)      { s = Wv; d = Wvb; }
    else if (j < 2048) { s = Wk; d = Wkb; j -= 1024; }
    else               { s = Wq; d = Wqb; j -= 2048; }
  }
  float4 f = ((const float4*)s)[j];
  ushort4 o; o.x = f2bf(f.x); o.y = f2bf(f.y); o.z = f2bf(f.z); o.w = f2bf(f.w);
  ((ushort4*)d)[j] = o;
}

// ---------------- K1: projections via MFMA, full-E row blocks ----------------
// grid = mat(3) x ns(16) x ttile(16 of 32 tokens) = 768 blocks, 256 threads.
// Stage 32 tokens x 1024 dims (all heads) once; W frags register-resident per
// wave (W shared by all heads); wave w computes heads 4w..4w+3.
// k/q: results written back into consumed LDS columns, swept out coalesced.
// v: stored transposed vpT[ns][h][d][l].
__global__ void __launch_bounds__(256) proj_kernel(
    const float* __restrict__ vals, const float* __restrict__ keys,
    const float* __restrict__ qry,
    const u16* __restrict__ Wvb, const u16* __restrict__ Wkb,
    const u16* __restrict__ Wqb,
    u16* __restrict__ vpT, u16* __restrict__ kp, u16* __restrict__ qp) {
  const int b = blockIdx.x;
  const int tt = b & 15, ns = (b >> 4) & 15, mat = b >> 8;
  const int tid = threadIdx.x;
  const float* src = (mat == 0 ? vals : mat == 1 ? keys : qry);
  const u16*   W   = (mat == 0 ? Wvb  : mat == 1 ? Wkb  : Wqb);
  __shared__ u16 Xs[32][1032];          // row stride 516 words (516%32=4): clean
  const size_t gbase = ((size_t)(ns*LL + tt*32))*EE;
  #pragma unroll 8
  for (int j = 0; j < 32; ++j) {        // one token row per iter, fully coalesced
    float4 f = *(const float4*)&src[gbase + (size_t)j*EE + tid*4];
    ushort4 o; o.x = f2bf(f.x); o.y = f2bf(f.y); o.z = f2bf(f.z); o.w = f2bf(f.w);
    *(ushort4*)&Xs[j][tid*4] = o;
  }
  const int wid = tid >> 6, lane = tid & 63, quad = lane >> 4, l16 = lane & 15;
  // W fragments: all 4 n-tiles, k=64 (2 chunks). Reused across all 4 heads.
  bf16x8 wf[4][2];
  #pragma unroll
  for (int nt = 0; nt < 4; ++nt) {
    wf[nt][0] = *(const bf16x8*)&W[(nt*16 + l16)*DD + quad*8];
    wf[nt][1] = *(const bf16x8*)&W[(nt*16 + l16)*DD + 32 + quad*8];
  }
  f32x4 z = {0.f, 0.f, 0.f, 0.f};
  __syncthreads();
  const float sc = (mat == 2) ? SCALE_Q : 1.f;
  #pragma unroll
  for (int hh = 0; hh < 4; ++hh) {
    const int h = wid*4 + hh;
    bf16x8 af[2][2];
    #pragma unroll
    for (int m = 0; m < 2; ++m) {
      af[m][0] = *(const bf16x8*)&Xs[m*16 + l16][h*DD + quad*8];
      af[m][1] = *(const bf16x8*)&Xs[m*16 + l16][h*DD + 32 + quad*8];
    }
    f32x4 acc[2][4];
    #pragma unroll
    for (int m = 0; m < 2; ++m)
      #pragma unroll
      for (int nt = 0; nt < 4; ++nt) {
        acc[m][nt] = MFMA32(af[m][0], wf[nt][0], z);
        acc[m][nt] = MFMA32(af[m][1], wf[nt][1], acc[m][nt]);
      }
    if (mat == 0) {
      // transposed store: rows d, 4 consecutive tokens as ushort4
      #pragma unroll
      for (int m = 0; m < 2; ++m)
        #pragma unroll
        for (int nt = 0; nt < 4; ++nt) {
          ushort4 o;
          o.x = f2bf(acc[m][nt][0]); o.y = f2bf(acc[m][nt][1]);
          o.z = f2bf(acc[m][nt][2]); o.w = f2bf(acc[m][nt][3]);
          size_t idx = ((size_t)((ns*HH + h)*DD + nt*16 + l16))*LL
                       + tt*32 + m*16 + quad*4;
          *(ushort4*)&vpT[idx] = o;
        }
    } else {
      // write back into this wave's own (already consumed) column block
      #pragma unroll
      for (int m = 0; m < 2; ++m)
        #pragma unroll
        for (int nt = 0; nt < 4; ++nt)
          #pragma unroll
          for (int r = 0; r < 4; ++r)
            Xs[m*16 + quad*4 + r][h*DD + nt*16 + l16] = f2bf(acc[m][nt][r] * sc);
    }
  }
  if (mat != 0) {
    u16* dst = (mat == 1 ? kp : qp);
    __syncthreads();
    #pragma unroll
    for (int i = tid; i < 4096; i += 256) {    // 32 rows x 128 segs of 16B
      int row = i >> 7, seg = (i & 127) * 8;
      *(bf16x8*)&dst[gbase + (size_t)row*EE + seg] = *(const bf16x8*)&Xs[row][seg];
    }
  }
}

// ---------------- K2: fused column-softmax + attention-out ----------------
// one block per (ns,h): 256 blocks x 1024 threads. K resident in LDS; V chunk
// double-buffered; P via per-wave LDS transpose; MFMA32 only.
// softmax is over the QUERY axis: colsum_l = sum_q mask_q * exp2(e_ql).
__global__ void __launch_bounds__(1024, 4) attn_kernel(
    const u16* __restrict__ qp, const u16* __restrict__ kp,
    const u16* __restrict__ vpT, const int* __restrict__ mask,
    u16* __restrict__ oat) {
  const int b = blockIdx.x;
  const int h = b & 15, ns = b >> 4;
  const int tid = threadIdx.x;
  const int wid = tid >> 6, lane = tid & 63, quad = lane >> 4, l16 = lane & 15;
  __shared__ u16 Ks[LL][72];        // K[l][d]      73728 B
  __shared__ u16 Vt[2][DD][72];     // V^T[d][l64]  18432 B
  __shared__ u16 pt[16][32][40];    // per-wave P   40960 B (phase A: psum f32[16][512])
  __shared__ float csum[LL];        //               2048 B   => 135168 B total
  float* psum = (float*)pt;
  // ---- stage K ----
  const size_t kgbase = ((size_t)(ns*LL))*EE + h*DD;
  for (int i = tid; i < 4096; i += 1024) {          // 512 rows x 8 segs of 16B
    int row = i >> 3, seg = (i & 7) * 8;
    *(bf16x8*)&Ks[row][seg] = *(const bf16x8*)&kp[kgbase + (size_t)row*EE + seg];
  }
  // ---- persistent Q fragments (wave owns 32 q rows) + masks ----
  const int q0 = wid*32;
  bf16x8 qf[2][2];
  float maf[2][4];
  #pragma unroll
  for (int qt = 0; qt < 2; ++qt) {
    const u16* qrow = qp + ((size_t)(ns*LL + q0 + qt*16 + l16))*EE + h*DD;
    qf[qt][0] = *(const bf16x8*)&qrow[quad*8];
    qf[qt][1] = *(const bf16x8*)&qrow[32 + quad*8];
    #pragma unroll
    for (int r = 0; r < 4; ++r)
      maf[qt][r] = mask[ns*LL + q0 + qt*16 + quad*4 + r] ? 1.f : 0.f;
  }
  f32x4 z = {0.f, 0.f, 0.f, 0.f};
  __syncthreads();
  // ---- phase A: column partial sums -> psum[wid][l], then block reduce ----
  for (int lt = 0; lt < 32; ++lt) {
    bf16x8 kf0 = *(const bf16x8*)&Ks[lt*16 + l16][quad*8];
    bf16x8 kf1 = *(const bf16x8*)&Ks[lt*16 + l16][32 + quad*8];
    float part = 0.f;
    #pragma unroll
    for (int qt = 0; qt < 2; ++qt) {
      f32x4 e = MFMA32(qf[qt][0], kf0, z);
      e = MFMA32(qf[qt][1], kf1, e);
      #pragma unroll
      for (int r = 0; r < 4; ++r)
        part += maf[qt][r] * FEXP2(e[r]);     // e row = q(quad*4+r), col = l(l16)
    }
    part += __shfl_xor(part, 16);             // combine 4 quads (same l16)
    part += __shfl_xor(part, 32);
    if (quad == 0) psum[wid*512 + lt*16 + l16] = part;
  }
  __syncthreads();
  if (tid < LL) {
    float s = 0.f;
    #pragma unroll
    for (int w = 0; w < 16; ++w) s += psum[w*512 + tid];
    csum[tid] = (s > 0.f) ? 1.f/s : 0.f;
  }
  __syncthreads();
  // ---- phase B: E recompute -> P (LDS transpose) -> PV, V chunks of 64 l ----
  f32x4 acc[4][2] = {{z,z},{z,z},{z,z},{z,z}};   // [dtile][qt]
  const size_t vgbase = ((size_t)((ns*HH + h)*DD))*LL;
  for (int lc = 0; lc < 8; ++lc) {               // 8 chunks of 64 l
    if (tid < 512) {                             // stage V^T[d][lc*64..+63]
      int row = tid >> 3, seg = (tid & 7) * 8;
      *(bf16x8*)&Vt[lc & 1][row][seg] =
          *(const bf16x8*)&vpT[vgbase + (size_t)row*LL + lc*64 + seg];
    }
    __syncthreads();                             // one barrier per chunk (dbuf)
    // E + P for 64 l in 4 sub-tiles of 16
    #pragma unroll
    for (int lt2 = 0; lt2 < 4; ++lt2) {
      const int lrow = lc*64 + lt2*16 + l16;
      bf16x8 kf0 = *(const bf16x8*)&Ks[lrow][quad*8];
      bf16x8 kf1 = *(const bf16x8*)&Ks[lrow][32 + quad*8];
      const float csv = csum[lrow];
      #pragma unroll
      for (int qt = 0; qt < 2; ++qt) {
        f32x4 e = MFMA32(qf[qt][0], kf0, z);
        e = MFMA32(qf[qt][1], kf1, e);
        #pragma unroll
        for (int r = 0; r < 4; ++r)
          pt[wid][qt*16 + quad*4 + r][lt2 & 1 ? 16 + l16 : l16] =
              f2bf(maf[qt][r] * csv * FEXP2(e[r]));
        // PV for the 32-l half once both sub-tiles of it are in pt
        if (lt2 & 1) {
          bf16x8 pa = *(const bf16x8*)&pt[wid][qt*16 + l16][quad*8];
          #pragma unroll
          for (int dt = 0; dt < 4; ++dt) {
            bf16x8 vb = *(const bf16x8*)&Vt[lc & 1][dt*16 + l16]
                                        [(lt2 >> 1)*32 + quad*8];
            acc[dt][qt] = MFMA32(pa, vb, acc[dt][qt]);
          }
        }
      }
    }
  }
  // ---- write out[q][d]: D row = q(quad*4+r), col = d(l16) ----
  #pragma unroll
  for (int qt = 0; qt < 2; ++qt)
    #pragma unroll
    for (int dt = 0; dt < 4; ++dt)
      #pragma unroll
      for (int r = 0; r < 4; ++r)
        oat[((size_t)(ns*LL + q0 + qt*16 + quad*4 + r))*EE + h*DD + dt*16 + l16] =
            f2bf(acc[dt][qt][r]);
}

// ---------------- K4: Y = oat @ Wo^T + bo, LDS-tiled MFMA GEMM ----------------
// 128x128 tile, BK=64, 4 waves each computing a 64x64 quadrant.
__global__ void __launch_bounds__(256) out_gemm_kernel(
    const u16* __restrict__ A, const u16* __restrict__ Wob,
    const float* __restrict__ bo, float* __restrict__ Y) {
  __shared__ u16 As[128][72];   // [m][k]  18432 B
  __shared__ u16 Bs[128][72];   // [n][k]  18432 B
  const int b = blockIdx.x;     // 64 mtiles x 8 ntiles
  const int nb = b & 7, mb = b >> 3;
  const int m0 = mb*128, n0 = nb*128;
  const int tid = threadIdx.x;
  const int wid = tid >> 6, lane = tid & 63, quad = lane >> 4, l16 = lane & 15;
  const int wm = (wid >> 1)*64, wn = (wid & 1)*64;   // wave quadrant
  f32x4 z = {0.f, 0.f, 0.f, 0.f};
  f32x4 acc[4][4];
  #pragma unroll
  for (int i = 0; i < 4; ++i)
    #pragma unroll
    for (int j = 0; j < 4; ++j) acc[i][j] = z;
  for (int k0 = 0; k0 < EE; k0 += 64) {
    __syncthreads();
    #pragma unroll
    for (int it = 0; it < 4; ++it) {      // stage 128 rows x 64 k each
      int idx = it*256 + tid;
      int row = idx >> 3, seg = (idx & 7) * 8;
      *(bf16x8*)&As[row][seg] = *(const bf16x8*)&A  [(size_t)(m0 + row)*EE + k0 + seg];
      *(bf16x8*)&Bs[row][seg] = *(const bf16x8*)&Wob[(size_t)(n0 + row)*EE + k0 + seg];
    }
    __syncthreads();
    #pragma unroll
    for (int kk = 0; kk < 2; ++kk) {
      bf16x8 af[4], bfr[4];
      #pragma unroll
      for (int i = 0; i < 4; ++i)
        af[i] = *(const bf16x8*)&As[wm + i*16 + l16][kk*32 + quad*8];
      #pragma unroll
      for (int j = 0; j < 4; ++j)
        bfr[j] = *(const bf16x8*)&Bs[wn + j*16 + l16][kk*32 + quad*8];
      #pragma unroll
      for (int i = 0; i < 4; ++i)
        #pragma unroll
        for (int j = 0; j < 4; ++j)
          acc[i][j] = MFMA32(af[i], bfr[j], acc[i][j]);
    }
  }
  #pragma unroll
  for (int i = 0; i < 4; ++i)
    #pragma unroll
    for (int j = 0; j < 4; ++j) {
      int col = n0 + wn + j*16 + l16;
      float bias = bo[col];
      #pragma unroll
      for (int r = 0; r < 4; ++r)
        Y[(size_t)(m0 + wm + i*16 + quad*4 + r)*EE + col] = acc[i][j][r] + bias;
    }
}

extern "C" void kernel_launch(void* const* d_in, const int* in_sizes, int n_in,
                              void* d_out, int out_size, void* d_ws, size_t ws_size,
                              hipStream_t stream) {
  const float* values = (const float*)d_in[0];
  const float* keysp  = (const float*)d_in[1];
  const float* query  = (const float*)d_in[2];
  const int*   mask   = (const int*)d_in[3];
  const float* Wv = (const float*)d_in[4];
  const float* Wk = (const float*)d_in[5];
  const float* Wq = (const float*)d_in[6];
  const float* Wo = (const float*)d_in[7];
  const float* bo = (const float*)d_in[8];
  float* Y = (float*)d_out;

  u16* qp  = (u16*)d_ws;
  u16* kp  = qp + NSLE;
  u16* vpT = kp + NSLE;
  u16* oat = vpT + NSLE;
  u16* Wob = oat + NSLE;
  u16* Wvb = Wob + EE*EE;
  u16* Wkb = Wvb + DD*DD;
  u16* Wqb = Wkb + DD*DD;

  convw_kernel<<<1036, 256, 0, stream>>>(Wv, Wk, Wq, Wo, Wvb, Wkb, Wqb, Wob);
  proj_kernel<<<3*NSX*16, 256, 0, stream>>>(values, keysp, query,
                                            Wvb, Wkb, Wqb, vpT, kp, qp);
  attn_kernel<<<NSX*HH, 1024, 0, stream>>>(qp, kp, vpT, mask, oat);
  out_gemm_kernel<<<(NT/128)*(EE/128), 256, 0, stream>>>(oat, Wob, bo, Y);
}